// Round 3
// baseline (338.948 us; speedup 1.0000x reference)
//
#include <hip/hip_runtime.h>
#include <hip/hip_bf16.h>

// Problem constants
#define CIN   128
#define COUT  128
#define DD    36
#define HW    5184
#define DHW   186624          // 36*5184 ; attn per-channel plane is L*81 = same
#define PATCH 9
#define NPW   576             // patches per d-slab (HW/9)
#define L_TOT 2304
#define PP    81
#define LDSK  136             // padded k stride (128 + 8) in bf16 elems

typedef __attribute__((ext_vector_type(8))) short bf16x8;
typedef __attribute__((ext_vector_type(4))) float f32x4;

__device__ __forceinline__ short f2bf(float f) {
    unsigned u = __builtin_bit_cast(unsigned, f);
    unsigned r = (u + 0x7fffu + ((u >> 16) & 1u)) >> 16;
    return (short)r;
}
__device__ __forceinline__ float bf2f(short s) {
    unsigned u = ((unsigned)(unsigned short)s) << 16;
    return __builtin_bit_cast(float, u);
}

// ---------------------------------------------------------------------------
// Kernel 1: per-(c,l) nonzero count -> inv table (1.18 MB in workspace).
// Coalesced: block owns 256 rows = 20736 floats, float4 grid loads,
// predicates packed to LDS, per-thread 81-byte LDS row sum.
// ---------------------------------------------------------------------------
__global__ __launch_bounds__(256) void count_nz(
    const float* __restrict__ attn, float* __restrict__ inv)
{
    __shared__ unsigned int pred[5184];   // 20736 predicate bytes
    const int t = threadIdx.x;
    const float4* g = (const float4*)(attn + (size_t)blockIdx.x * 20736);
    #pragma unroll
    for (int k = 0; k < 20; ++k) {
        const int idx = k * 256 + t;
        const float4 v = g[idx];
        pred[idx] = (v.x != 0.f ? 1u : 0u) | (v.y != 0.f ? 0x100u : 0u)
                  | (v.z != 0.f ? 0x10000u : 0u) | (v.w != 0.f ? 0x1000000u : 0u);
    }
    if (t < 64) {
        const int idx = 5120 + t;
        const float4 v = g[idx];
        pred[idx] = (v.x != 0.f ? 1u : 0u) | (v.y != 0.f ? 0x100u : 0u)
                  | (v.z != 0.f ? 0x10000u : 0u) | (v.w != 0.f ? 0x1000000u : 0u);
    }
    __syncthreads();
    const unsigned char* pb = (const unsigned char*)pred + t * PP;
    int cnt = 0;
    #pragma unroll
    for (int q = 0; q < PP; ++q) cnt += pb[q];
    inv[(size_t)blockIdx.x * 256 + t] = 1.0f / ((float)cnt + 1e-5f);
}

// ---------------------------------------------------------------------------
// Kernel 2: fused 1x1x1-conv GEMM + attention epilogue.
// Block = Cout 128 x hw-tile 64 at one d-row. Swizzle: ii (= d % 9) fastest,
// so the 9 blocks sharing an attn footprint are dispatch-adjacent (L2/L3 hits).
// attn slice (bf16) + inv prefetched into LDS at block start to hide scatter
// latency behind staging + MFMA.
// ---------------------------------------------------------------------------
__global__ __launch_bounds__(256, 4) void fused_main(
    const float* __restrict__ x,     // [128][36][5184]
    const float* __restrict__ attn,  // [128][2304][81]
    const float* __restrict__ W,     // [128][128]
    const float* __restrict__ bia,   // [128]
    const float* __restrict__ inv,   // [128][2304]
    float* __restrict__ out)         // [128][36][5184]
{
    __shared__ __align__(16) short xs[64][LDSK];  // 17408 B: x tile, [n][k] bf16
    __shared__ short sa[1024 * 9];                // 18432 B: attn[c][lp][jj] bf16
    __shared__ float invs[1024];                  //  4096 B: inv[c][lp]

    const int t    = threadIdx.x;
    const int wv   = t >> 6;
    const int lane = t & 63;
    const int col  = lane & 15;
    const int quad = lane >> 4;

    const int ii     = blockIdx.x % 9;        // fastest: attn-line reuse window
    const int rest   = blockIdx.x / 9;
    const int hwblk  = rest % 81;
    const int pd     = rest / 81;
    const int d      = pd * 9 + ii;
    const int hwbase = hwblk * 64;
    const int p0     = hwbase / 9;            // first patch this tile touches
    const int l0     = pd * NPW + p0;         // lp in [0,8) always in-range

    // ---- prefetch attn slice + inv into LDS (independent of GEMM path) ----
    #pragma unroll
    for (int k = 0; k < 4; ++k) {
        const int pr = k * 256 + t;           // pr = c*8 + lp
        const int c  = pr >> 3, lp = pr & 7;
        const float* ap = attn + (size_t)c * DHW + (size_t)(l0 + lp) * PP + ii * 9;
        invs[pr] = inv[c * L_TOT + l0 + lp];
        #pragma unroll
        for (int q = 0; q < 9; ++q)
            sa[pr * 9 + q] = f2bf(ap[q]);
    }

    // ---- stage x[:, d, hwbase..+64) -> LDS transposed bf16 [n][k] ----
    #pragma unroll
    for (int e = t; e < 2048; e += 256) {
        const int row = e >> 4;               // cin
        const int f4  = e & 15;
        const float4 v = *(const float4*)(x + (size_t)row * DHW + (size_t)d * HW
                                          + hwbase + f4 * 4);
        const int n0 = f4 * 4;
        xs[n0 + 0][row] = f2bf(v.x);
        xs[n0 + 1][row] = f2bf(v.y);
        xs[n0 + 2][row] = f2bf(v.z);
        xs[n0 + 3][row] = f2bf(v.w);
    }

    // ---- A fragments (W rows, bf16) + bias for this wave's Cout tile ----
    const int wbase = wv * 32;
    bf16x8 afrag[2][4];
    #pragma unroll
    for (int mt = 0; mt < 2; ++mt) {
        const int m = wbase + mt * 16 + col;
        #pragma unroll
        for (int s = 0; s < 4; ++s) {
            const float4* wp4 = (const float4*)(W + m * 128 + s * 32 + quad * 8);
            float4 w0 = wp4[0], w1 = wp4[1];
            bf16x8 f;
            f[0] = f2bf(w0.x); f[1] = f2bf(w0.y); f[2] = f2bf(w0.z); f[3] = f2bf(w0.w);
            f[4] = f2bf(w1.x); f[5] = f2bf(w1.y); f[6] = f2bf(w1.z); f[7] = f2bf(w1.w);
            afrag[mt][s] = f;
        }
    }
    float bias[2][4];
    #pragma unroll
    for (int mt = 0; mt < 2; ++mt)
        #pragma unroll
        for (int r = 0; r < 4; ++r)
            bias[mt][r] = bia[wbase + mt * 16 + quad * 4 + r];

    __syncthreads();

    // ---- GEMM: 128(Cout) x 64(n) x 128(K), 16x16x32 MFMA ----
    f32x4 acc[2][4];
    #pragma unroll
    for (int mt = 0; mt < 2; ++mt)
        #pragma unroll
        for (int tt = 0; tt < 4; ++tt)
            acc[mt][tt] = (f32x4){0.f, 0.f, 0.f, 0.f};

    #pragma unroll
    for (int s = 0; s < 4; ++s) {
        bf16x8 bfrag[4];
        #pragma unroll
        for (int tt = 0; tt < 4; ++tt)
            bfrag[tt] = *(const bf16x8*)&xs[tt * 16 + col][s * 32 + quad * 8];
        #pragma unroll
        for (int mt = 0; mt < 2; ++mt)
            #pragma unroll
            for (int tt = 0; tt < 4; ++tt)
                acc[mt][tt] = __builtin_amdgcn_mfma_f32_16x16x32_bf16(
                    afrag[mt][s], bfrag[tt], acc[mt][tt], 0, 0, 0);
    }

    // ---- epilogue: y=acc+bias ; out = lrelu(y*(y + a*inv + 1)) ----
    #pragma unroll
    for (int tt = 0; tt < 4; ++tt) {
        const int hw = hwbase + tt * 16 + col;
        const int p  = hw / 9;
        const int jj = hw - p * 9;
        const int lp = p - p0;
        #pragma unroll
        for (int mt = 0; mt < 2; ++mt) {
            #pragma unroll
            for (int r = 0; r < 4; ++r) {
                const int c  = wbase + mt * 16 + quad * 4 + r;
                const int pr = c * 8 + lp;
                const float y = acc[mt][tt][r] + bias[mt][r];
                const float a = bf2f(sa[pr * 9 + jj]);
                const float v = y * (y + a * invs[pr] + 1.0f);
                out[(size_t)c * DHW + (size_t)d * HW + hw] =
                    (v >= 0.f) ? v : 0.2f * v;
            }
        }
    }
}

// ---------------------------------------------------------------------------
// Fallback (round-1 kernel, known-good) if ws can't hold the inv table.
// ---------------------------------------------------------------------------
__global__ __launch_bounds__(256) void fused_cross_head_fallback(
    const float* __restrict__ x, const float* __restrict__ attn,
    const float* __restrict__ W, const float* __restrict__ bia,
    float* __restrict__ out)
{
    __shared__ __align__(16) short xs[2][48][LDSK];
    __shared__ float inv_lds[COUT][4];

    const int t = threadIdx.x, wv = t >> 6, lane = t & 63;
    const int col = lane & 15, quad = lane >> 4;
    const int blk = blockIdx.x;
    const int pd = blk / 144, hwblk = blk - pd * 144;
    const int hwbase = hwblk * 36;
    const int lbase = pd * NPW + hwblk * 4;

    for (int pair = t; pair < 512; pair += 256) {
        const int c = pair >> 2, p = pair & 3;
        const float* ap = attn + (size_t)c * DHW + (size_t)(lbase + p) * PP;
        int cnt = 0;
        #pragma unroll 27
        for (int q = 0; q < PP; ++q) cnt += (ap[q] != 0.0f) ? 1 : 0;
        inv_lds[c][p] = 1.0f / ((float)cnt + 1e-5f);
    }
    const int wbase = wv * 32;
    bf16x8 afrag[2][4];
    #pragma unroll
    for (int mt = 0; mt < 2; ++mt) {
        const int m = wbase + mt * 16 + col;
        #pragma unroll
        for (int s = 0; s < 4; ++s) {
            const float4* wp4 = (const float4*)(W + m * 128 + s * 32 + quad * 8);
            float4 w0 = wp4[0], w1 = wp4[1];
            bf16x8 f;
            f[0] = f2bf(w0.x); f[1] = f2bf(w0.y); f[2] = f2bf(w0.z); f[3] = f2bf(w0.w);
            f[4] = f2bf(w1.x); f[5] = f2bf(w1.y); f[6] = f2bf(w1.z); f[7] = f2bf(w1.w);
            afrag[mt][s] = f;
        }
    }
    float bias[2][4];
    #pragma unroll
    for (int mt = 0; mt < 2; ++mt)
        #pragma unroll
        for (int r = 0; r < 4; ++r)
            bias[mt][r] = bia[wbase + mt * 16 + quad * 4 + r];

    for (int i = 0; i < 9; ++i) {
        const int buf = i & 1;
        const int d = pd * PATCH + i;
        for (int e = t; e < 1152; e += 256) {
            const int row = e / 9, f4 = e - row * 9;
            const float4 v = *(const float4*)(x + (size_t)row * DHW + (size_t)d * HW
                                              + hwbase + f4 * 4);
            const int n0 = f4 * 4;
            xs[buf][n0 + 0][row] = f2bf(v.x);
            xs[buf][n0 + 1][row] = f2bf(v.y);
            xs[buf][n0 + 2][row] = f2bf(v.z);
            xs[buf][n0 + 3][row] = f2bf(v.w);
        }
        __syncthreads();
        f32x4 acc[2][3];
        #pragma unroll
        for (int mt = 0; mt < 2; ++mt)
            #pragma unroll
            for (int tt = 0; tt < 3; ++tt)
                acc[mt][tt] = (f32x4){0.f, 0.f, 0.f, 0.f};
        #pragma unroll
        for (int s = 0; s < 4; ++s) {
            bf16x8 bfrag[3];
            #pragma unroll
            for (int tt = 0; tt < 3; ++tt)
                bfrag[tt] = *(const bf16x8*)&xs[buf][tt * 16 + col][s * 32 + quad * 8];
            #pragma unroll
            for (int mt = 0; mt < 2; ++mt)
                #pragma unroll
                for (int tt = 0; tt < 3; ++tt)
                    acc[mt][tt] = __builtin_amdgcn_mfma_f32_16x16x32_bf16(
                        afrag[mt][s], bfrag[tt], acc[mt][tt], 0, 0, 0);
        }
        #pragma unroll
        for (int tt = 0; tt < 3; ++tt) {
            const int n = tt * 16 + col;
            if (n < 36) {
                const int p = n / 9, jj = n - p * 9, kk = i * 9 + jj;
                #pragma unroll
                for (int mt = 0; mt < 2; ++mt) {
                    #pragma unroll
                    for (int r = 0; r < 4; ++r) {
                        const int c = wbase + mt * 16 + quad * 4 + r;
                        const float y = acc[mt][tt][r] + bias[mt][r];
                        const float a = attn[(size_t)c * DHW + (size_t)(lbase + p) * PP + kk];
                        const float v = y * (y + a * inv_lds[c][p] + 1.0f);
                        out[(size_t)c * DHW + (size_t)d * HW + hwbase + n] =
                            (v >= 0.f) ? v : 0.2f * v;
                    }
                }
            }
        }
    }
}

extern "C" void kernel_launch(void* const* d_in, const int* in_sizes, int n_in,
                              void* d_out, int out_size, void* d_ws, size_t ws_size,
                              hipStream_t stream) {
    const float* x    = (const float*)d_in[0];
    const float* attn = (const float*)d_in[1];
    const float* W    = (const float*)d_in[2];
    const float* b    = (const float*)d_in[3];
    float* out        = (float*)d_out;

    const size_t inv_bytes = (size_t)COUT * L_TOT * sizeof(float);  // 1.18 MB
    if (ws_size >= inv_bytes) {
        float* inv = (float*)d_ws;
        count_nz<<<dim3((COUT * L_TOT) / 256), dim3(256), 0, stream>>>(attn, inv);
        fused_main<<<dim3(36 * 81), dim3(256), 0, stream>>>(x, attn, W, b, inv, out);
    } else {
        fused_cross_head_fallback<<<dim3(576), dim3(256), 0, stream>>>(x, attn, W, b, out);
    }
}